// Round 10
// baseline (199.538 us; speedup 1.0000x reference)
//
#include <hip/hip_runtime.h>
#include <hip/hip_bf16.h>
#include <math.h>

// GE2E loss: S=512 speakers, U=32 utt/speaker, D=1024, fp32 in, scalar f32 out.
#define S_ 512
#define U_ 32
#define D_ 1024
#define M_ (S_ * U_) // 16384 rows

typedef __attribute__((ext_vector_type(8))) short bf16x8;
typedef __attribute__((ext_vector_type(4))) float f32x4;

// fp32 -> bf16 round-to-nearest-even (software; prep kernel only)
__device__ __forceinline__ unsigned int f2bf(float f) {
    union { float f; unsigned u; } v; v.f = f;
    return (v.u + 0x7FFFu + ((v.u >> 16) & 1u)) >> 16;
}

// 8x fp32 -> bf16x8 via HW packed convert (RNE), for the no-ebf fallback
__device__ __forceinline__ bf16x8 cvt8(float4 u, float4 v) {
    union { bf16x8 b; unsigned r[4]; } o;
    asm("v_cvt_pk_bf16_f32 %0, %1, %2" : "=v"(o.r[0]) : "v"(u.x), "v"(u.y));
    asm("v_cvt_pk_bf16_f32 %0, %1, %2" : "=v"(o.r[1]) : "v"(u.z), "v"(u.w));
    asm("v_cvt_pk_bf16_f32 %0, %1, %2" : "=v"(o.r[2]) : "v"(v.x), "v"(v.y));
    asm("v_cvt_pk_bf16_f32 %0, %1, %2" : "=v"(o.r[3]) : "v"(v.z), "v"(v.w));
    return o.b;
}

// ---------------------------------------------------------------------------
// Prep kernel: one BW-bound pass over emb producing
//   ebf[r][d]  bf16 embeddings (32 MB) for direct MFMA A-fragment loads
//   rn2[r]     exact fp32 squared row norms
//   cib[s][d]  bf16 unit inclusive centroid (1 MB)
//   csn[s]     fp32 ||csum||
// Wave w owns utterances w*8..w*8+7; lane l owns d-chunk [16l,16l+16).
// Per-u reduction is a 64-lane shuffle chain (no cross-wave work).
// ---------------------------------------------------------------------------
__global__ __launch_bounds__(256) void ge2e_prep(
    const float* __restrict__ emb, unsigned short* __restrict__ ebf,
    unsigned short* __restrict__ cib, float* __restrict__ rn2,
    float* __restrict__ csn, int writeEbf)
{
    const int s = blockIdx.x, t = threadIdx.x, w = t >> 6, l = t & 63;
    __shared__ float scs[4][1024];   // per-wave partial centroid sums (16 KB)
    __shared__ float red[4];

    float cs[16];
    #pragma unroll
    for (int i = 0; i < 16; ++i) cs[i] = 0.f;

    for (int uu = 0; uu < 8; ++uu) {
        const int u = w * 8 + uu;
        const size_t roff = ((size_t)s * U_ + u) * D_ + l * 16;
        const float4* rp = (const float4*)(emb + roff);
        const float4 v0 = rp[0], v1 = rp[1], v2 = rp[2], v3 = rp[3];

        cs[0] += v0.x; cs[1] += v0.y; cs[2]  += v0.z; cs[3]  += v0.w;
        cs[4] += v1.x; cs[5] += v1.y; cs[6]  += v1.z; cs[7]  += v1.w;
        cs[8] += v2.x; cs[9] += v2.y; cs[10] += v2.z; cs[11] += v2.w;
        cs[12] += v3.x; cs[13] += v3.y; cs[14] += v3.z; cs[15] += v3.w;

        float q = v0.x * v0.x + v0.y * v0.y + v0.z * v0.z + v0.w * v0.w;
        q += v1.x * v1.x + v1.y * v1.y + v1.z * v1.z + v1.w * v1.w;
        q += v2.x * v2.x + v2.y * v2.y + v2.z * v2.z + v2.w * v2.w;
        q += v3.x * v3.x + v3.y * v3.y + v3.z * v3.z + v3.w * v3.w;
        #pragma unroll
        for (int m = 1; m < 64; m <<= 1) q += __shfl_xor(q, m);
        if (l == 0) rn2[s * U_ + u] = q;

        if (writeEbf) {
            uint4 p0, p1;
            p0.x = f2bf(v0.x) | (f2bf(v0.y) << 16);
            p0.y = f2bf(v0.z) | (f2bf(v0.w) << 16);
            p0.z = f2bf(v1.x) | (f2bf(v1.y) << 16);
            p0.w = f2bf(v1.z) | (f2bf(v1.w) << 16);
            p1.x = f2bf(v2.x) | (f2bf(v2.y) << 16);
            p1.y = f2bf(v2.z) | (f2bf(v2.w) << 16);
            p1.z = f2bf(v3.x) | (f2bf(v3.y) << 16);
            p1.w = f2bf(v3.z) | (f2bf(v3.w) << 16);
            *(uint4*)(ebf + roff) = p0;
            *(uint4*)(ebf + roff + 8) = p1;
        }
    }

    #pragma unroll
    for (int i = 0; i < 16; ++i) scs[w][l * 16 + i] = cs[i];
    __syncthreads();

    // combine waves; thread t owns d-range [4t, 4t+4)
    float4 p0 = *(const float4*)&scs[0][t * 4];
    float4 p1 = *(const float4*)&scs[1][t * 4];
    float4 p2 = *(const float4*)&scs[2][t * 4];
    float4 p3 = *(const float4*)&scs[3][t * 4];
    float4 tot;
    tot.x = p0.x + p1.x + p2.x + p3.x;
    tot.y = p0.y + p1.y + p2.y + p3.y;
    tot.z = p0.z + p1.z + p2.z + p3.z;
    tot.w = p0.w + p1.w + p2.w + p3.w;

    float cn = tot.x * tot.x + tot.y * tot.y + tot.z * tot.z + tot.w * tot.w;
    #pragma unroll
    for (int m = 1; m < 64; m <<= 1) cn += __shfl_xor(cn, m);
    if (l == 0) red[w] = cn;
    __syncthreads();

    const float csn2 = red[0] + red[1] + red[2] + red[3];
    const float inv = rsqrtf(csn2);
    if (t == 0) csn[s] = sqrtf(csn2);

    ushort4 o;
    o.x = (unsigned short)f2bf(tot.x * inv);
    o.y = (unsigned short)f2bf(tot.y * inv);
    o.z = (unsigned short)f2bf(tot.z * inv);
    o.w = (unsigned short)f2bf(tot.w * inv);
    *(ushort4*)(cib + (size_t)s * D_ + t * 4) = o;
}

// ---------------------------------------------------------------------------
// GEMM + LOO diag + LSE + loss. ZERO LDS / ZERO barriers in the K-loop:
// each lane loads its MFMA A- and B-fragments directly from global (bf16,
// 16B/lane). 512 thr / 8 waves; wave w owns cols [w*64, w*64+64);
// 2 M-frags x 4 N-frags; 32 K-steps, fully unrolled, 3-slot register
// rotation (loads issued 2 steps ahead; all offsets compile-time).
// A rows are shared by all 8 waves -> L1/L2 hits after first touch.
// mfma_f32_16x16x32_bf16: A/B lane l -> row/col=l&15, k=(l>>4)*8+j;
// C/D lane l -> col=l&15, row=(l>>4)*4+reg (m89-verified).
// ---------------------------------------------------------------------------
template<int USE_EBF>
__global__ __launch_bounds__(512, 4) void ge2e_mfma_lse(
    const float* __restrict__ emb, const unsigned short* __restrict__ ebf,
    const unsigned short* __restrict__ cib,
    const float* __restrict__ rn2, const float* __restrict__ csn,
    const float* __restrict__ wp, const float* __restrict__ bp,
    float* __restrict__ lossAcc)
{
    __shared__ float sMax[32][8], sSum[32][8], sTgt[32];

    const int t = threadIdx.x;
    const int row0 = blockIdx.x * 32;
    const int w = t >> 6, l = t & 63, g = l >> 4, c = l & 15;

    // fragment base pointers (k advances by ks*32 elements = 64 B immediates)
    const unsigned short* aB0 = ebf + (size_t)(row0 + c) * D_ + g * 8;
    const unsigned short* aB1 = aB0 + (size_t)16 * D_;
    const float* aF0 = emb + (size_t)(row0 + c) * D_ + g * 8;
    const float* aF1 = aF0 + (size_t)16 * D_;
    const unsigned short* bB = cib + (size_t)(w * 64 + c) * D_ + g * 8;

    f32x4 acc[2][4];
    #pragma unroll
    for (int m = 0; m < 2; ++m)
        #pragma unroll
        for (int n = 0; n < 4; ++n) acc[m][n] = (f32x4){0.f, 0.f, 0.f, 0.f};

    bf16x8 as[3][2], bs[3][4];

#define LOADK(slot, kk) do {                                               \
        if (USE_EBF) {                                                     \
            as[slot][0] = *(const bf16x8*)(aB0 + (kk) * 32);               \
            as[slot][1] = *(const bf16x8*)(aB1 + (kk) * 32);               \
        } else {                                                           \
            const float4* p0 = (const float4*)(aF0 + (kk) * 32);           \
            const float4* p1 = (const float4*)(aF1 + (kk) * 32);           \
            as[slot][0] = cvt8(p0[0], p0[1]);                              \
            as[slot][1] = cvt8(p1[0], p1[1]);                              \
        }                                                                  \
        bs[slot][0] = *(const bf16x8*)(bB + (kk) * 32);                    \
        bs[slot][1] = *(const bf16x8*)(bB + (size_t)16 * D_ + (kk) * 32);  \
        bs[slot][2] = *(const bf16x8*)(bB + (size_t)32 * D_ + (kk) * 32);  \
        bs[slot][3] = *(const bf16x8*)(bB + (size_t)48 * D_ + (kk) * 32);  \
    } while (0)

    LOADK(0, 0);
    LOADK(1, 1);

    #pragma unroll
    for (int ks = 0; ks < 32; ++ks) {
        if (ks + 2 < 32) LOADK((ks + 2) % 3, ks + 2);
        const int cu = ks % 3;
        #pragma unroll
        for (int n = 0; n < 4; ++n) {
            acc[0][n] = __builtin_amdgcn_mfma_f32_16x16x32_bf16(as[cu][0], bs[cu][n], acc[0][n], 0, 0, 0);
            acc[1][n] = __builtin_amdgcn_mfma_f32_16x16x32_bf16(as[cu][1], bs[cu][n], acc[1][n], 0, 0, 0);
        }
    }
#undef LOADK

    // ---------------- epilogue: diag LOO + per-row LSE + loss ----------------
    const float W = wp[0], Bb = bp[0];
    const int s = blockIdx.x;
    const int wsid = s >> 6, jn = (s >> 4) & 3, cdiag = s & 15;
    const float csnv = csn[s];
    const bool dlane = (w == wsid) && (c == cdiag);

    #pragma unroll
    for (int m = 0; m < 2; ++m) {
        #pragma unroll
        for (int r = 0; r < 4; ++r) {
            const int lr = m * 16 + g * 4 + r;        // local row
            const float rn2v = rn2[row0 + lr];
            const float invr = rsqrtf(rn2v);
            float vals[4], mx = -1e30f, tgt = 0.f;
            #pragma unroll
            for (int n = 0; n < 4; ++n) {
                const float a = acc[m][n][r];
                float sim = a * invr;
                if (dlane && n == jn) {
                    // leave-one-out: (e.csum - |e|^2) / (|e| * |csum - e|)
                    const float dotv = a * csnv;
                    const float ex2 = fmaxf(csnv * csnv - 2.f * dotv + rn2v, 1e-12f);
                    sim = (dotv - rn2v) * invr * rsqrtf(ex2);
                }
                const float lg = fmaf(W, sim, Bb);
                vals[n] = lg;
                if (dlane && n == jn) tgt = lg;
                mx = fmaxf(mx, lg);
            }
            #pragma unroll
            for (int msk = 1; msk < 16; msk <<= 1) mx = fmaxf(mx, __shfl_xor(mx, msk));
            float se = 0.f;
            #pragma unroll
            for (int n = 0; n < 4; ++n) se += expf(vals[n] - mx);
            #pragma unroll
            for (int msk = 1; msk < 16; msk <<= 1) se += __shfl_xor(se, msk);
            if (c == 0) { sMax[lr][w] = mx; sSum[lr][w] = se; }
            if (dlane) sTgt[lr] = tgt;
        }
    }
    __syncthreads();

    if (t < 32) {
        float Mx = -1e30f;
        #pragma unroll
        for (int q = 0; q < 8; ++q) Mx = fmaxf(Mx, sMax[t][q]);
        float Ss = 0.f;
        #pragma unroll
        for (int q = 0; q < 8; ++q) Ss += sSum[t][q] * expf(sMax[t][q] - Mx);
        float contrib = Mx + logf(Ss) - sTgt[t];
        #pragma unroll
        for (int msk = 1; msk < 32; msk <<= 1) contrib += __shfl_xor(contrib, msk);
        if (t == 0) atomicAdd(lossAcc, contrib);
    }
}

// ---------------------------------------------------------------------------
__global__ void ge2e_final(const float* __restrict__ lossAcc, float* __restrict__ out)
{
    out[0] = lossAcc[0] * (1.0f / (float)M_);
}

extern "C" void kernel_launch(void* const* d_in, const int* in_sizes, int n_in,
                              void* d_out, int out_size, void* d_ws, size_t ws_size,
                              hipStream_t stream)
{
    const float* emb = (const float*)d_in[0];
    const float* wp  = (const float*)d_in[1];
    const float* bp  = (const float*)d_in[2];

    float* ws = (float*)d_ws;
    float* rn2     = ws;                         // 16384 f
    float* csn     = ws + 16384;                 // 512 f
    float* lossAcc = ws + 16896;                 // 1 f (+3 pad)
    unsigned short* cib = (unsigned short*)(ws + 16900);  // 1 MB, 16B-aligned
    unsigned short* ebf = cib + (size_t)S_ * D_;          // 32 MB, 16B-aligned

    const size_t need = (size_t)16900 * 4 + (size_t)S_ * D_ * 2 + (size_t)M_ * D_ * 2;
    const int useEbf = (ws_size >= need) ? 1 : 0;

    hipMemsetAsync(lossAcc, 0, sizeof(float), stream);

    ge2e_prep<<<S_, 256, 0, stream>>>(emb, ebf, cib, rn2, csn, useEbf);
    if (useEbf)
        ge2e_mfma_lse<1><<<M_ / 32, 512, 0, stream>>>(emb, ebf, cib, rn2, csn, wp, bp, lossAcc);
    else
        ge2e_mfma_lse<0><<<M_ / 32, 512, 0, stream>>>(emb, ebf, cib, rn2, csn, wp, bp, lossAcc);
    ge2e_final<<<1, 1, 0, stream>>>(lossAcc, (float*)d_out);
}

// Round 12
// 161.892 us; speedup vs baseline: 1.2325x; 1.2325x over previous
//
#include <hip/hip_runtime.h>
#include <hip/hip_bf16.h>
#include <math.h>

// GE2E loss: S=512 speakers, U=32 utt/speaker, D=1024, fp32 in, scalar f32 out.
#define S_ 512
#define U_ 32
#define D_ 1024
#define M_ (S_ * U_) // 16384 rows

typedef __attribute__((ext_vector_type(8))) short bf16x8;
typedef __attribute__((ext_vector_type(4))) float f32x4;

__device__ __forceinline__ unsigned int f2bf(float f) {
    union { float f; unsigned u; } v; v.f = f;
    return (v.u + 0x7FFFu + ((v.u >> 16) & 1u)) >> 16;
}
__device__ __forceinline__ bf16x8 cvt8(float4 u, float4 v) {
    union { bf16x8 b; unsigned r[4]; } o;
    asm("v_cvt_pk_bf16_f32 %0, %1, %2" : "=v"(o.r[0]) : "v"(u.x), "v"(u.y));
    asm("v_cvt_pk_bf16_f32 %0, %1, %2" : "=v"(o.r[1]) : "v"(u.z), "v"(u.w));
    asm("v_cvt_pk_bf16_f32 %0, %1, %2" : "=v"(o.r[2]) : "v"(v.x), "v"(v.y));
    asm("v_cvt_pk_bf16_f32 %0, %1, %2" : "=v"(o.r[3]) : "v"(v.z), "v"(v.w));
    return o.b;
}

// ===========================================================================
// FAST PATH (needs ~34.8 MB workspace)
// Tiled layouts (16B "unit" = what one lane stages/reads):
//   A: ebf_t unit index ((panel*32+kc)*8 + fi)*64 + g*16 + r15
//      holds emb row (panel*128 + fi*16 + r15), k = kc*32 + g*8 .. +8  (bf16)
//   B: cib_t unit index ((cp*32+kc)*8 + nf)*64 + g*16 + c15
//      holds centroid col (cp*128 + nf*16 + c15), same k slice.
// One (panel,kc) tile = 512 contiguous units = 8 KB -> linear staging,
// LDS frag read = lane*16B (canonical conflict-free ds_read_b128).
// ===========================================================================

// ---- prep: centroids + rn2 + tiled bf16 A/B ------------------------------
__global__ __launch_bounds__(256) void ge2e_prep_t(
    const float* __restrict__ emb, unsigned short* __restrict__ ebf_t,
    unsigned short* __restrict__ cib_t, float* __restrict__ rn2,
    float* __restrict__ csn)
{
    const int s = blockIdx.x, t = threadIdx.x, w = t >> 6, l = t & 63;
    __shared__ __align__(16) unsigned short tile[32][1032]; // +8 pad: 16B-aligned rows, bank-spread
    __shared__ float sRnP[32][4];
    __shared__ float red[4];
    __shared__ __align__(16) unsigned short crow[1024];

    const float* base = emb + (size_t)s * 32 * D_;
    float cx = 0.f, cy = 0.f, cz = 0.f, cw = 0.f;

    for (int u = 0; u < 32; ++u) {
        float4 v = *(const float4*)(base + u * D_ + t * 4); // coalesced
        cx += v.x; cy += v.y; cz += v.z; cw += v.w;
        float q = v.x * v.x + v.y * v.y + v.z * v.z + v.w * v.w;
        #pragma unroll
        for (int m = 1; m < 64; m <<= 1) q += __shfl_xor(q, m);
        if (l == 0) sRnP[u][w] = q;
        ushort4 o;
        o.x = (unsigned short)f2bf(v.x); o.y = (unsigned short)f2bf(v.y);
        o.z = (unsigned short)f2bf(v.z); o.w = (unsigned short)f2bf(v.w);
        *(ushort4*)&tile[u][t * 4] = o;
    }
    float cn = cx * cx + cy * cy + cz * cz + cw * cw;
    #pragma unroll
    for (int m = 1; m < 64; m <<= 1) cn += __shfl_xor(cn, m);
    if (l == 0) red[w] = cn;
    __syncthreads();

    if (t < 32) rn2[s * 32 + t] = sRnP[t][0] + sRnP[t][1] + sRnP[t][2] + sRnP[t][3];

    const float csn2 = red[0] + red[1] + red[2] + red[3];
    const float inv = rsqrtf(csn2);
    if (t == 0) csn[s] = sqrtf(csn2);
    {
        ushort4 o;
        o.x = (unsigned short)f2bf(cx * inv); o.y = (unsigned short)f2bf(cy * inv);
        o.z = (unsigned short)f2bf(cz * inv); o.w = (unsigned short)f2bf(cw * inv);
        *(ushort4*)&crow[t * 4] = o;
    }
    __syncthreads();

    // phase2: tiled A writes (4096 units, coalesced: consecutive t -> consecutive units)
    const int fiBase = (s & 3) * 2;
    const size_t panel = (size_t)(s >> 2);
    #pragma unroll
    for (int it = 0; it < 16; ++it) {
        const int unit = it * 256 + t;
        const int kc = unit >> 7, rem = unit & 127;
        const int lfi = rem >> 6, gg = (rem >> 4) & 3, r15 = rem & 15;
        const int row = lfi * 16 + r15;
        const int k0 = kc * 32 + gg * 8;
        uint4 d = *(const uint4*)&tile[row][k0];
        const size_t gu = ((panel * 32 + kc) * 8 + fiBase + lfi) * 64 + gg * 16 + r15;
        *(uint4*)(ebf_t + gu * 8) = d;
    }
    // tiled B (this block owns centroid column s): 128 units
    if (t < 128) {
        const int kc = t >> 2, gg = t & 3;
        const int cp = s >> 7, nf = (s & 127) >> 4, c15 = s & 15;
        uint4 d = *(const uint4*)&crow[t * 8];
        const size_t gu = (((size_t)(cp * 32 + kc)) * 8 + nf) * 64 + gg * 16 + c15;
        *(uint4*)(cib_t + gu * 8) = d;
    }
}

// ---- GEMM (m97 structure): 128x128 tile, BK=32, 4 waves, 1 barrier/step --
__global__ __launch_bounds__(256, 3) void ge2e_gemm_t(
    const unsigned short* __restrict__ ebf_t, const unsigned short* __restrict__ cib_t,
    const float* __restrict__ rn2, const float* __restrict__ csn,
    const float* __restrict__ wp, const float* __restrict__ bp,
    float* __restrict__ rowsum, float* __restrict__ tgt)
{
    __shared__ __align__(16) short sA[2][4096]; // 8 KB per buf
    __shared__ __align__(16) short sB[2][4096];
    __shared__ float sRn2[128];
    __shared__ float sPart[128][2];

    const int t = threadIdx.x, w = t >> 6, l = t & 63;
    const int wm = w >> 1, wn = w & 1, g = l >> 4, c = l & 15;
    const int bid = blockIdx.x, brow = bid >> 2, bcol = bid & 3;

    const unsigned short* At = ebf_t + (size_t)(brow * 32) * 4096; // +kc*4096 shorts
    const unsigned short* Bt = cib_t + (size_t)(bcol * 32) * 4096;

    if (t < 128) sRn2[t] = rn2[brow * 128 + t];

    f32x4 acc[4][4];
    #pragma unroll
    for (int i = 0; i < 4; ++i)
        #pragma unroll
        for (int j = 0; j < 4; ++j) acc[i][j] = (f32x4){0.f, 0.f, 0.f, 0.f};

    uint4 ra0, ra1, rb0, rb1;
#define LOADREG(kc) { const unsigned short* a_ = At + (kc) * 4096; \
                      const unsigned short* b_ = Bt + (kc) * 4096; \
                      ra0 = *(const uint4*)(a_ + t * 8);        \
                      ra1 = *(const uint4*)(a_ + 2048 + t * 8); \
                      rb0 = *(const uint4*)(b_ + t * 8);        \
                      rb1 = *(const uint4*)(b_ + 2048 + t * 8); }
#define WRITELDS(buf) { *(uint4*)&sA[buf][t * 8] = ra0; *(uint4*)&sA[buf][2048 + t * 8] = ra1; \
                        *(uint4*)&sB[buf][t * 8] = rb0; *(uint4*)&sB[buf][2048 + t * 8] = rb1; }

    LOADREG(0); WRITELDS(0);
    __syncthreads();

    for (int kc = 0; kc < 32; ++kc) {
        const int cb = kc & 1;
        if (kc < 31) LOADREG(kc + 1);          // issue next-tile loads
        bf16x8 af[4], bb[4];
        #pragma unroll
        for (int i = 0; i < 4; ++i) {
            af[i] = *(const bf16x8*)&sA[cb][((wm * 4 + i) * 64 + l) * 8];
            bb[i] = *(const bf16x8*)&sB[cb][((wn * 4 + i) * 64 + l) * 8];
        }
        __builtin_amdgcn_s_setprio(1);
        #pragma unroll
        for (int i = 0; i < 4; ++i)
            #pragma unroll
            for (int j = 0; j < 4; ++j)
                acc[i][j] = __builtin_amdgcn_mfma_f32_16x16x32_bf16(af[i], bb[j], acc[i][j], 0, 0, 0);
        __builtin_amdgcn_s_setprio(0);
        if (kc < 31) WRITELDS(cb ^ 1);         // compiler inserts vmcnt wait here
        __syncthreads();
    }
#undef LOADREG
#undef WRITELDS

    // ---- epilogue: logits -> fixed-shift exp-sum (+LOO diag) -> atomics ----
    const float W = wp[0], Bb = bp[0];
    const float Cs = Bb + fabsf(W);            // upper bound of any logit
    #pragma unroll
    for (int mi = 0; mi < 4; ++mi) {
        #pragma unroll
        for (int r = 0; r < 4; ++r) {
            const int row_local = wm * 64 + mi * 16 + g * 4 + r;
            const int gr = brow * 128 + row_local;
            const int sid = gr >> 5;
            const float rn2v = sRn2[row_local];
            const float invr = rsqrtf(rn2v);
            float se = 0.f;
            #pragma unroll
            for (int ni = 0; ni < 4; ++ni) {
                const int col = bcol * 128 + wn * 64 + ni * 16 + c;
                const float a = acc[mi][ni][r];
                float sim = a * invr;
                if (col == sid) {
                    const float csnv = csn[sid];
                    const float dotv = a * csnv;
                    const float ex2 = fmaxf(csnv * csnv - 2.f * dotv + rn2v, 1e-12f);
                    sim = (dotv - rn2v) * invr * rsqrtf(ex2);
                }
                const float lg = fmaf(W, sim, Bb);
                if (col == sid) tgt[gr] = lg;
                se += expf(lg - Cs);
            }
            #pragma unroll
            for (int m = 1; m < 16; m <<= 1) se += __shfl_xor(se, m);
            if (c == 0) sPart[row_local][wn] = se;
        }
    }
    __syncthreads();
    if (t < 128) atomicAdd(&rowsum[brow * 128 + t], sPart[t][0] + sPart[t][1]);
}

// ---- LSE + loss reduce ----------------------------------------------------
__global__ __launch_bounds__(256) void ge2e_lse(
    const float* __restrict__ rowsum, const float* __restrict__ tgt,
    const float* __restrict__ wp, const float* __restrict__ bp,
    float* __restrict__ lossAcc)
{
    __shared__ float red[4];
    const int t = threadIdx.x, gr = blockIdx.x * 256 + t;
    const float Cs = bp[0] + fabsf(wp[0]);
    float contrib = logf(rowsum[gr]) + Cs - tgt[gr];
    #pragma unroll
    for (int m = 1; m < 64; m <<= 1) contrib += __shfl_xor(contrib, m);
    if ((t & 63) == 0) red[t >> 6] = contrib;
    __syncthreads();
    if (t == 0) atomicAdd(lossAcc, red[0] + red[1] + red[2] + red[3]);
}

__global__ void ge2e_final(const float* __restrict__ lossAcc, float* __restrict__ out)
{
    out[0] = lossAcc[0] * (1.0f / (float)M_);
}

// ===========================================================================
// FALLBACK PATH (R10, verified on HW: ~100 us kernel) — used if ws too small
// ===========================================================================
__global__ __launch_bounds__(256) void ge2e_prep_fb(
    const float* __restrict__ emb, unsigned short* __restrict__ cib,
    float* __restrict__ rn2, float* __restrict__ csn)
{
    const int s = blockIdx.x, t = threadIdx.x, w = t >> 6, l = t & 63;
    __shared__ float scs[4][1024];
    __shared__ float red[4];
    float cs[16];
    #pragma unroll
    for (int i = 0; i < 16; ++i) cs[i] = 0.f;
    for (int uu = 0; uu < 8; ++uu) {
        const int u = w * 8 + uu;
        const size_t roff = ((size_t)s * U_ + u) * D_ + l * 16;
        const float4* rp = (const float4*)(emb + roff);
        const float4 v0 = rp[0], v1 = rp[1], v2 = rp[2], v3 = rp[3];
        cs[0] += v0.x; cs[1] += v0.y; cs[2] += v0.z; cs[3] += v0.w;
        cs[4] += v1.x; cs[5] += v1.y; cs[6] += v1.z; cs[7] += v1.w;
        cs[8] += v2.x; cs[9] += v2.y; cs[10] += v2.z; cs[11] += v2.w;
        cs[12] += v3.x; cs[13] += v3.y; cs[14] += v3.z; cs[15] += v3.w;
        float q = v0.x*v0.x + v0.y*v0.y + v0.z*v0.z + v0.w*v0.w
                + v1.x*v1.x + v1.y*v1.y + v1.z*v1.z + v1.w*v1.w
                + v2.x*v2.x + v2.y*v2.y + v2.z*v2.z + v2.w*v2.w
                + v3.x*v3.x + v3.y*v3.y + v3.z*v3.z + v3.w*v3.w;
        #pragma unroll
        for (int m = 1; m < 64; m <<= 1) q += __shfl_xor(q, m);
        if (l == 0) rn2[s * U_ + u] = q;
    }
    #pragma unroll
    for (int i = 0; i < 16; ++i) scs[w][l * 16 + i] = cs[i];
    __syncthreads();
    float4 p0 = *(const float4*)&scs[0][t * 4], p1 = *(const float4*)&scs[1][t * 4];
    float4 p2 = *(const float4*)&scs[2][t * 4], p3 = *(const float4*)&scs[3][t * 4];
    float4 tot; tot.x = p0.x+p1.x+p2.x+p3.x; tot.y = p0.y+p1.y+p2.y+p3.y;
    tot.z = p0.z+p1.z+p2.z+p3.z; tot.w = p0.w+p1.w+p2.w+p3.w;
    float cn = tot.x*tot.x + tot.y*tot.y + tot.z*tot.z + tot.w*tot.w;
    #pragma unroll
    for (int m = 1; m < 64; m <<= 1) cn += __shfl_xor(cn, m);
    if (l == 0) red[w] = cn;
    __syncthreads();
    const float csn2 = red[0] + red[1] + red[2] + red[3];
    const float inv = rsqrtf(csn2);
    if (t == 0) csn[s] = sqrtf(csn2);
    ushort4 o;
    o.x = (unsigned short)f2bf(tot.x * inv); o.y = (unsigned short)f2bf(tot.y * inv);
    o.z = (unsigned short)f2bf(tot.z * inv); o.w = (unsigned short)f2bf(tot.w * inv);
    *(ushort4*)(cib + (size_t)s * D_ + t * 4) = o;
}

__global__ __launch_bounds__(512, 4) void ge2e_fused_fb(
    const float* __restrict__ emb, const unsigned short* __restrict__ cib,
    const float* __restrict__ rn2, const float* __restrict__ csn,
    const float* __restrict__ wp, const float* __restrict__ bp,
    float* __restrict__ lossAcc)
{
    __shared__ float sMax[32][8], sSum[32][8], sTgt[32];
    const int t = threadIdx.x, row0 = blockIdx.x * 32;
    const int w = t >> 6, l = t & 63, g = l >> 4, c = l & 15;
    const float* aF0 = emb + (size_t)(row0 + c) * D_ + g * 8;
    const float* aF1 = aF0 + (size_t)16 * D_;
    const unsigned short* bB = cib + (size_t)(w * 64 + c) * D_ + g * 8;
    f32x4 acc[2][4];
    #pragma unroll
    for (int m = 0; m < 2; ++m)
        #pragma unroll
        for (int n = 0; n < 4; ++n) acc[m][n] = (f32x4){0.f, 0.f, 0.f, 0.f};
    bf16x8 as[3][2], bs[3][4];
#define LOADK(slot, kk) do { \
        const float4* p0 = (const float4*)(aF0 + (kk) * 32); \
        const float4* p1 = (const float4*)(aF1 + (kk) * 32); \
        as[slot][0] = cvt8(p0[0], p0[1]); as[slot][1] = cvt8(p1[0], p1[1]); \
        bs[slot][0] = *(const bf16x8*)(bB + (kk) * 32); \
        bs[slot][1] = *(const bf16x8*)(bB + (size_t)16 * D_ + (kk) * 32); \
        bs[slot][2] = *(const bf16x8*)(bB + (size_t)32 * D_ + (kk) * 32); \
        bs[slot][3] = *(const bf16x8*)(bB + (size_t)48 * D_ + (kk) * 32); } while (0)
    LOADK(0, 0); LOADK(1, 1);
    #pragma unroll
    for (int ks = 0; ks < 32; ++ks) {
        if (ks + 2 < 32) LOADK((ks + 2) % 3, ks + 2);
        const int cu = ks % 3;
        #pragma unroll
        for (int n = 0; n < 4; ++n) {
            acc[0][n] = __builtin_amdgcn_mfma_f32_16x16x32_bf16(as[cu][0], bs[cu][n], acc[0][n], 0, 0, 0);
            acc[1][n] = __builtin_amdgcn_mfma_f32_16x16x32_bf16(as[cu][1], bs[cu][n], acc[1][n], 0, 0, 0);
        }
    }
#undef LOADK
    const float W = wp[0], Bb = bp[0];
    const int s = blockIdx.x, wsid = s >> 6, jn = (s >> 4) & 3, cdiag = s & 15;
    const float csnv = csn[s];
    const bool dlane = (w == wsid) && (c == cdiag);
    #pragma unroll
    for (int m = 0; m < 2; ++m) {
        #pragma unroll
        for (int r = 0; r < 4; ++r) {
            const int lr = m * 16 + g * 4 + r;
            const float rn2v = rn2[row0 + lr];
            const float invr = rsqrtf(rn2v);
            float vals[4], mx = -1e30f, tg = 0.f;
            #pragma unroll
            for (int n = 0; n < 4; ++n) {
                const float a = acc[m][n][r];
                float sim = a * invr;
                if (dlane && n == jn) {
                    const float dotv = a * csnv;
                    const float ex2 = fmaxf(csnv * csnv - 2.f * dotv + rn2v, 1e-12f);
                    sim = (dotv - rn2v) * invr * rsqrtf(ex2);
                }
                const float lg = fmaf(W, sim, Bb);
                vals[n] = lg;
                if (dlane && n == jn) tg = lg;
                mx = fmaxf(mx, lg);
            }
            #pragma unroll
            for (int msk = 1; msk < 16; msk <<= 1) mx = fmaxf(mx, __shfl_xor(mx, msk));
            float se = 0.f;
            #pragma unroll
            for (int n = 0; n < 4; ++n) se += expf(vals[n] - mx);
            #pragma unroll
            for (int msk = 1; msk < 16; msk <<= 1) se += __shfl_xor(se, msk);
            if (c == 0) { sMax[lr][w] = mx; sSum[lr][w] = se; }
            if (dlane) sTgt[lr] = tg;
        }
    }
    __syncthreads();
    if (t < 32) {
        float Mx = -1e30f;
        #pragma unroll
        for (int q = 0; q < 8; ++q) Mx = fmaxf(Mx, sMax[t][q]);
        float Ss = 0.f;
        #pragma unroll
        for (int q = 0; q < 8; ++q) Ss += sSum[t][q] * expf(sMax[t][q] - Mx);
        float contrib = Mx + logf(Ss) - sTgt[t];
        #pragma unroll
        for (int msk = 1; msk < 32; msk <<= 1) contrib += __shfl_xor(contrib, msk);
        if (t == 0) atomicAdd(lossAcc, contrib);
    }
}

// ===========================================================================
extern "C" void kernel_launch(void* const* d_in, const int* in_sizes, int n_in,
                              void* d_out, int out_size, void* d_ws, size_t ws_size,
                              hipStream_t stream)
{
    const float* emb = (const float*)d_in[0];
    const float* wp  = (const float*)d_in[1];
    const float* bp  = (const float*)d_in[2];

    float* ws = (float*)d_ws;
    float* rn2     = ws;                          // 16384 f
    float* csn     = ws + 16384;                  //   512 f
    float* rowsum  = ws + 16896;                  // 16384 f
    float* tgt     = ws + 33280;                  // 16384 f
    float* lossAcc = ws + 49664;                  //     1 f (+3 pad)
    unsigned short* cib_t = (unsigned short*)(ws + 49668);   // 1 MB (16B-aligned)
    unsigned short* ebf_t = cib_t + (size_t)S_ * D_;         // 32 MB

    const size_t need = (size_t)49668 * 4 + (size_t)S_ * D_ * 2 + (size_t)M_ * D_ * 2;

    hipMemsetAsync(lossAcc, 0, sizeof(float), stream);

    if (ws_size >= need) {
        hipMemsetAsync(rowsum, 0, M_ * sizeof(float), stream);
        ge2e_prep_t<<<S_, 256, 0, stream>>>(emb, ebf_t, cib_t, rn2, csn);
        ge2e_gemm_t<<<(M_ / 128) * 4, 256, 0, stream>>>(ebf_t, cib_t, rn2, csn, wp, bp, rowsum, tgt);
        ge2e_lse<<<M_ / 256, 256, 0, stream>>>(rowsum, tgt, wp, bp, lossAcc);
    } else {
        unsigned short* cib = (unsigned short*)(ws + 16900);
        ge2e_prep_fb<<<S_, 256, 0, stream>>>(emb, cib, rn2, csn);
        ge2e_fused_fb<<<M_ / 32, 512, 0, stream>>>(emb, cib, rn2, csn, wp, bp, lossAcc);
    }
    ge2e_final<<<1, 1, 0, stream>>>(lossAcc, (float*)d_out);
}

// Round 14
// 146.062 us; speedup vs baseline: 1.3661x; 1.1084x over previous
//
#include <hip/hip_runtime.h>
#include <hip/hip_bf16.h>
#include <math.h>

// GE2E loss: S=512 speakers, U=32 utt/speaker, D=1024, fp32 in, scalar f32 out.
#define S_ 512
#define U_ 32
#define D_ 1024
#define M_ (S_ * U_) // 16384 rows

typedef __attribute__((ext_vector_type(8))) short bf16x8;
typedef __attribute__((ext_vector_type(4))) float f32x4;

__device__ __forceinline__ unsigned int f2bf(float f) {
    union { float f; unsigned u; } v; v.f = f;
    return (v.u + 0x7FFFu + ((v.u >> 16) & 1u)) >> 16;
}
__device__ __forceinline__ bf16x8 cvt8(float4 u, float4 v) {
    union { bf16x8 b; unsigned r[4]; } o;
    asm("v_cvt_pk_bf16_f32 %0, %1, %2" : "=v"(o.r[0]) : "v"(u.x), "v"(u.y));
    asm("v_cvt_pk_bf16_f32 %0, %1, %2" : "=v"(o.r[1]) : "v"(u.z), "v"(u.w));
    asm("v_cvt_pk_bf16_f32 %0, %1, %2" : "=v"(o.r[2]) : "v"(v.x), "v"(v.y));
    asm("v_cvt_pk_bf16_f32 %0, %1, %2" : "=v"(o.r[3]) : "v"(v.z), "v"(v.w));
    return o.b;
}

// ===========================================================================
// FAST PATH. Tiled layouts (16B "unit" = what one lane stages/reads):
//   A: ebf_t unit ((panel*32+kc)*8 + fi)*64 + g*16 + r15
//      holds emb row (panel*128 + fi*16 + r15), k = kc*32 + g*8 .. +8 (bf16)
//   B: cib_t unit ((cp*32+kc)*8 + nf)*64 + g*16 + c15  (centroid cols)
// One (panel,kc) tile = 512 contiguous units = 8 KB.
// ===========================================================================

// ---- prep: 512 blocks (1/speaker), two 16-row phases through a 33 KB tile.
// q[u] register partials -> 16 independent shuffle chains (no per-u serial).
__global__ __launch_bounds__(256) void ge2e_prep_t(
    const float* __restrict__ emb, unsigned short* __restrict__ ebf_t,
    unsigned short* __restrict__ cib_t, float* __restrict__ rn2,
    float* __restrict__ csn)
{
    const int s = blockIdx.x, t = threadIdx.x, w = t >> 6, l = t & 63;
    __shared__ __align__(16) unsigned short tile[16][1032]; // 33 KB (16B-aligned rows)
    __shared__ float sqw[16][4];
    __shared__ float red[4];
    __shared__ __align__(16) unsigned short crow[1024];

    const int panel = s >> 2;
    float4 psum = make_float4(0.f, 0.f, 0.f, 0.f);

    #pragma unroll
    for (int P = 0; P < 2; ++P) {
        const float* base = emb + ((size_t)s * 32 + P * 16) * D_ + t * 4;
        float q[16];
        #pragma unroll
        for (int u = 0; u < 16; ++u) {
            float4 v = *(const float4*)(base + (size_t)u * D_);   // coalesced 16B/lane
            psum.x += v.x; psum.y += v.y; psum.z += v.z; psum.w += v.w;
            q[u] = v.x * v.x + v.y * v.y + v.z * v.z + v.w * v.w;
            ushort4 o;
            o.x = (unsigned short)f2bf(v.x); o.y = (unsigned short)f2bf(v.y);
            o.z = (unsigned short)f2bf(v.z); o.w = (unsigned short)f2bf(v.w);
            *(ushort4*)&tile[u][t * 4] = o;
        }
        // 16 independent 6-shuffle chains -> per-wave partials
        #pragma unroll
        for (int u = 0; u < 16; ++u) {
            float qq = q[u];
            #pragma unroll
            for (int m = 1; m < 64; m <<= 1) qq += __shfl_xor(qq, m);
            if (l == 0) sqw[u][w] = qq;
        }
        __syncthreads();                       // tile + sqw ready
        if (t < 16) rn2[s * 32 + P * 16 + t] = sqw[t][0] + sqw[t][1] + sqw[t][2] + sqw[t][3];
        // tiled A writes: 2048 units, consecutive t -> consecutive units (coalesced)
        const int fi = (s & 3) * 2 + P;
        #pragma unroll
        for (int it = 0; it < 8; ++it) {
            const int unit = it * 256 + t;
            const int kc = unit >> 6, g = (unit >> 4) & 3, r15 = unit & 15;
            uint4 d = *(const uint4*)&tile[r15][kc * 32 + g * 8];
            const size_t gu = (((size_t)(panel * 32 + kc)) * 8 + fi) * 64 + g * 16 + r15;
            *(uint4*)(ebf_t + gu * 8) = d;
        }
        __syncthreads();                       // tile consumed; safe to refill
    }

    // centroid finalize (psum = full csum slice [4t, 4t+4))
    float cn = psum.x * psum.x + psum.y * psum.y + psum.z * psum.z + psum.w * psum.w;
    #pragma unroll
    for (int m = 1; m < 64; m <<= 1) cn += __shfl_xor(cn, m);
    if (l == 0) red[w] = cn;
    __syncthreads();
    const float csn2 = red[0] + red[1] + red[2] + red[3];
    const float inv = rsqrtf(csn2);
    if (t == 0) csn[s] = sqrtf(csn2);
    {
        ushort4 o;
        o.x = (unsigned short)f2bf(psum.x * inv); o.y = (unsigned short)f2bf(psum.y * inv);
        o.z = (unsigned short)f2bf(psum.z * inv); o.w = (unsigned short)f2bf(psum.w * inv);
        *(ushort4*)&crow[t * 4] = o;
    }
    __syncthreads();
    if (t < 128) {                             // tiled B write (column s)
        const int kc = t >> 2, gg = t & 3;
        const int cp = s >> 7, nf = (s & 127) >> 4, c15 = s & 15;
        uint4 d = *(const uint4*)&crow[t * 8];
        const size_t gu = (((size_t)(cp * 32 + kc)) * 8 + nf) * 64 + gg * 16 + c15;
        *(uint4*)(cib_t + gu * 8) = d;
    }
}

// ---- GEMM (m97 structure, UNCHANGED from R12): 128x128, BK=32, 4 waves ----
__global__ __launch_bounds__(256, 3) void ge2e_gemm_t(
    const unsigned short* __restrict__ ebf_t, const unsigned short* __restrict__ cib_t,
    const float* __restrict__ rn2, const float* __restrict__ csn,
    const float* __restrict__ wp, const float* __restrict__ bp,
    float* __restrict__ rowsum, float* __restrict__ tgt)
{
    __shared__ __align__(16) short sA[2][4096];
    __shared__ __align__(16) short sB[2][4096];
    __shared__ float sRn2[128];
    __shared__ float sPart[128][2];

    const int t = threadIdx.x, w = t >> 6, l = t & 63;
    const int wm = w >> 1, wn = w & 1, g = l >> 4, c = l & 15;
    const int bid = blockIdx.x, brow = bid >> 2, bcol = bid & 3;

    const unsigned short* At = ebf_t + (size_t)(brow * 32) * 4096;
    const unsigned short* Bt = cib_t + (size_t)(bcol * 32) * 4096;

    if (t < 128) sRn2[t] = rn2[brow * 128 + t];

    f32x4 acc[4][4];
    #pragma unroll
    for (int i = 0; i < 4; ++i)
        #pragma unroll
        for (int j = 0; j < 4; ++j) acc[i][j] = (f32x4){0.f, 0.f, 0.f, 0.f};

    uint4 ra0, ra1, rb0, rb1;
#define LOADREG(kc) { const unsigned short* a_ = At + (kc) * 4096; \
                      const unsigned short* b_ = Bt + (kc) * 4096; \
                      ra0 = *(const uint4*)(a_ + t * 8);        \
                      ra1 = *(const uint4*)(a_ + 2048 + t * 8); \
                      rb0 = *(const uint4*)(b_ + t * 8);        \
                      rb1 = *(const uint4*)(b_ + 2048 + t * 8); }
#define WRITELDS(buf) { *(uint4*)&sA[buf][t * 8] = ra0; *(uint4*)&sA[buf][2048 + t * 8] = ra1; \
                        *(uint4*)&sB[buf][t * 8] = rb0; *(uint4*)&sB[buf][2048 + t * 8] = rb1; }

    LOADREG(0); WRITELDS(0);
    __syncthreads();

    for (int kc = 0; kc < 32; ++kc) {
        const int cb = kc & 1;
        if (kc < 31) LOADREG(kc + 1);
        bf16x8 af[4], bb[4];
        #pragma unroll
        for (int i = 0; i < 4; ++i) {
            af[i] = *(const bf16x8*)&sA[cb][((wm * 4 + i) * 64 + l) * 8];
            bb[i] = *(const bf16x8*)&sB[cb][((wn * 4 + i) * 64 + l) * 8];
        }
        __builtin_amdgcn_s_setprio(1);
        #pragma unroll
        for (int i = 0; i < 4; ++i)
            #pragma unroll
            for (int j = 0; j < 4; ++j)
                acc[i][j] = __builtin_amdgcn_mfma_f32_16x16x32_bf16(af[i], bb[j], acc[i][j], 0, 0, 0);
        __builtin_amdgcn_s_setprio(0);
        if (kc < 31) WRITELDS(cb ^ 1);
        __syncthreads();
    }
#undef LOADREG
#undef WRITELDS

    const float W = wp[0], Bb = bp[0];
    const float Cs = Bb + fabsf(W);
    #pragma unroll
    for (int mi = 0; mi < 4; ++mi) {
        #pragma unroll
        for (int r = 0; r < 4; ++r) {
            const int row_local = wm * 64 + mi * 16 + g * 4 + r;
            const int gr = brow * 128 + row_local;
            const int sid = gr >> 5;
            const float rn2v = sRn2[row_local];
            const float invr = rsqrtf(rn2v);
            float se = 0.f;
            #pragma unroll
            for (int ni = 0; ni < 4; ++ni) {
                const int col = bcol * 128 + wn * 64 + ni * 16 + c;
                const float a = acc[mi][ni][r];
                float sim = a * invr;
                if (col == sid) {
                    const float csnv = csn[sid];
                    const float dotv = a * csnv;
                    const float ex2 = fmaxf(csnv * csnv - 2.f * dotv + rn2v, 1e-12f);
                    sim = (dotv - rn2v) * invr * rsqrtf(ex2);
                }
                const float lg = fmaf(W, sim, Bb);
                if (col == sid) tgt[gr] = lg;
                se += expf(lg - Cs);
            }
            #pragma unroll
            for (int m = 1; m < 16; m <<= 1) se += __shfl_xor(se, m);
            if (c == 0) sPart[row_local][wn] = se;
        }
    }
    __syncthreads();
    if (t < 128) atomicAdd(&rowsum[brow * 128 + t], sPart[t][0] + sPart[t][1]);
}

// ---- LSE + loss reduce ----------------------------------------------------
__global__ __launch_bounds__(256) void ge2e_lse(
    const float* __restrict__ rowsum, const float* __restrict__ tgt,
    const float* __restrict__ wp, const float* __restrict__ bp,
    float* __restrict__ lossAcc)
{
    __shared__ float red[4];
    const int t = threadIdx.x, gr = blockIdx.x * 256 + t;
    const float Cs = bp[0] + fabsf(wp[0]);
    float contrib = logf(rowsum[gr]) + Cs - tgt[gr];
    #pragma unroll
    for (int m = 1; m < 64; m <<= 1) contrib += __shfl_xor(contrib, m);
    if ((t & 63) == 0) red[t >> 6] = contrib;
    __syncthreads();
    if (t == 0) atomicAdd(lossAcc, red[0] + red[1] + red[2] + red[3]);
}

__global__ void ge2e_final(const float* __restrict__ lossAcc, float* __restrict__ out)
{
    out[0] = lossAcc[0] * (1.0f / (float)M_);
}

// ===========================================================================
// FALLBACK PATH (unchanged, HW-verified) — used if ws too small
// ===========================================================================
__global__ __launch_bounds__(256) void ge2e_prep_fb(
    const float* __restrict__ emb, unsigned short* __restrict__ cib,
    float* __restrict__ rn2, float* __restrict__ csn)
{
    const int s = blockIdx.x, t = threadIdx.x, w = t >> 6, l = t & 63;
    __shared__ float scs[4][1024];
    __shared__ float red[4];
    float cs[16];
    #pragma unroll
    for (int i = 0; i < 16; ++i) cs[i] = 0.f;
    for (int uu = 0; uu < 8; ++uu) {
        const int u = w * 8 + uu;
        const size_t roff = ((size_t)s * U_ + u) * D_ + l * 16;
        const float4* rp = (const float4*)(emb + roff);
        const float4 v0 = rp[0], v1 = rp[1], v2 = rp[2], v3 = rp[3];
        cs[0] += v0.x; cs[1] += v0.y; cs[2] += v0.z; cs[3] += v0.w;
        cs[4] += v1.x; cs[5] += v1.y; cs[6] += v1.z; cs[7] += v1.w;
        cs[8] += v2.x; cs[9] += v2.y; cs[10] += v2.z; cs[11] += v2.w;
        cs[12] += v3.x; cs[13] += v3.y; cs[14] += v3.z; cs[15] += v3.w;
        float q = v0.x*v0.x + v0.y*v0.y + v0.z*v0.z + v0.w*v0.w
                + v1.x*v1.x + v1.y*v1.y + v1.z*v1.z + v1.w*v1.w
                + v2.x*v2.x + v2.y*v2.y + v2.z*v2.z + v2.w*v2.w
                + v3.x*v3.x + v3.y*v3.y + v3.z*v3.z + v3.w*v3.w;
        #pragma unroll
        for (int m = 1; m < 64; m <<= 1) q += __shfl_xor(q, m);
        if (l == 0) rn2[s * U_ + u] = q;
    }
    #pragma unroll
    for (int i = 0; i < 16; ++i) scs[w][l * 16 + i] = cs[i];
    __syncthreads();
    float4 p0 = *(const float4*)&scs[0][t * 4], p1 = *(const float4*)&scs[1][t * 4];
    float4 p2 = *(const float4*)&scs[2][t * 4], p3 = *(const float4*)&scs[3][t * 4];
    float4 tot; tot.x = p0.x+p1.x+p2.x+p3.x; tot.y = p0.y+p1.y+p2.y+p3.y;
    tot.z = p0.z+p1.z+p2.z+p3.z; tot.w = p0.w+p1.w+p2.w+p3.w;
    float cn = tot.x*tot.x + tot.y*tot.y + tot.z*tot.z + tot.w*tot.w;
    #pragma unroll
    for (int m = 1; m < 64; m <<= 1) cn += __shfl_xor(cn, m);
    if (l == 0) red[w] = cn;
    __syncthreads();
    const float csn2 = red[0] + red[1] + red[2] + red[3];
    const float inv = rsqrtf(csn2);
    if (t == 0) csn[s] = sqrtf(csn2);
    ushort4 o;
    o.x = (unsigned short)f2bf(tot.x * inv); o.y = (unsigned short)f2bf(tot.y * inv);
    o.z = (unsigned short)f2bf(tot.z * inv); o.w = (unsigned short)f2bf(tot.w * inv);
    *(ushort4*)(cib + (size_t)s * D_ + t * 4) = o;
}

__global__ __launch_bounds__(512, 4) void ge2e_fused_fb(
    const float* __restrict__ emb, const unsigned short* __restrict__ cib,
    const float* __restrict__ rn2, const float* __restrict__ csn,
    const float* __restrict__ wp, const float* __restrict__ bp,
    float* __restrict__ lossAcc)
{
    __shared__ float sMax[32][8], sSum[32][8], sTgt[32];
    const int t = threadIdx.x, row0 = blockIdx.x * 32;
    const int w = t >> 6, l = t & 63, g = l >> 4, c = l & 15;
    const float* aF0 = emb + (size_t)(row0 + c) * D_ + g * 8;
    const float* aF1 = aF0 + (size_t)16 * D_;
    const unsigned short* bB = cib + (size_t)(w * 64 + c) * D_ + g * 8;
    f32x4 acc[2][4];
    #pragma unroll
    for (int m = 0; m < 2; ++m)
        #pragma unroll
        for (int n = 0; n < 4; ++n) acc[m][n] = (f32x4){0.f, 0.f, 0.f, 0.f};
    bf16x8 as[3][2], bs[3][4];
#define LOADK(slot, kk) do { \
        const float4* p0 = (const float4*)(aF0 + (kk) * 32); \
        const float4* p1 = (const float4*)(aF1 + (kk) * 32); \
        as[slot][0] = cvt8(p0[0], p0[1]); as[slot][1] = cvt8(p1[0], p1[1]); \
        bs[slot][0] = *(const bf16x8*)(bB + (kk) * 32); \
        bs[slot][1] = *(const bf16x8*)(bB + (size_t)16 * D_ + (kk) * 32); \
        bs[slot][2] = *(const bf16x8*)(bB + (size_t)32 * D_ + (kk) * 32); \
        bs[slot][3] = *(const bf16x8*)(bB + (size_t)48 * D_ + (kk) * 32); } while (0)
    LOADK(0, 0); LOADK(1, 1);
    #pragma unroll
    for (int ks = 0; ks < 32; ++ks) {
        if (ks + 2 < 32) LOADK((ks + 2) % 3, ks + 2);
        const int cu = ks % 3;
        #pragma unroll
        for (int n = 0; n < 4; ++n) {
            acc[0][n] = __builtin_amdgcn_mfma_f32_16x16x32_bf16(as[cu][0], bs[cu][n], acc[0][n], 0, 0, 0);
            acc[1][n] = __builtin_amdgcn_mfma_f32_16x16x32_bf16(as[cu][1], bs[cu][n], acc[1][n], 0, 0, 0);
        }
    }
#undef LOADK
    const float W = wp[0], Bb = bp[0];
    const int s = blockIdx.x, wsid = s >> 6, jn = (s >> 4) & 3, cdiag = s & 15;
    const float csnv = csn[s];
    const bool dlane = (w == wsid) && (c == cdiag);
    #pragma unroll
    for (int m = 0; m < 2; ++m) {
        #pragma unroll
        for (int r = 0; r < 4; ++r) {
            const int lr = m * 16 + g * 4 + r;
            const float rn2v = rn2[row0 + lr];
            const float invr = rsqrtf(rn2v);
            float vals[4], mx = -1e30f, tg = 0.f;
            #pragma unroll
            for (int n = 0; n < 4; ++n) {
                const float a = acc[m][n][r];
                float sim = a * invr;
                if (dlane && n == jn) {
                    const float dotv = a * csnv;
                    const float ex2 = fmaxf(csnv * csnv - 2.f * dotv + rn2v, 1e-12f);
                    sim = (dotv - rn2v) * invr * rsqrtf(ex2);
                }
                const float lg = fmaf(W, sim, Bb);
                vals[n] = lg;
                if (dlane && n == jn) tg = lg;
                mx = fmaxf(mx, lg);
            }
            #pragma unroll
            for (int msk = 1; msk < 16; msk <<= 1) mx = fmaxf(mx, __shfl_xor(mx, msk));
            float se = 0.f;
            #pragma unroll
            for (int n = 0; n < 4; ++n) se += expf(vals[n] - mx);
            #pragma unroll
            for (int msk = 1; msk < 16; msk <<= 1) se += __shfl_xor(se, msk);
            if (c == 0) { sMax[lr][w] = mx; sSum[lr][w] = se; }
            if (dlane) sTgt[lr] = tg;
        }
    }
    __syncthreads();
    if (t < 32) {
        float Mx = -1e30f;
        #pragma unroll
        for (int q = 0; q < 8; ++q) Mx = fmaxf(Mx, sMax[t][q]);
        float Ss = 0.f;
        #pragma unroll
        for (int q = 0; q < 8; ++q) Ss += sSum[t][q] * expf(sMax[t][q] - Mx);
        float contrib = Mx + logf(Ss) - sTgt[t];
        #pragma unroll
        for (int msk = 1; msk < 32; msk <<= 1) contrib += __shfl_xor(contrib, msk);
        if (t == 0) atomicAdd(lossAcc, contrib);
    }
}

// ===========================================================================
extern "C" void kernel_launch(void* const* d_in, const int* in_sizes, int n_in,
                              void* d_out, int out_size, void* d_ws, size_t ws_size,
                              hipStream_t stream)
{
    const float* emb = (const float*)d_in[0];
    const float* wp  = (const float*)d_in[1];
    const float* bp  = (const float*)d_in[2];

    float* ws = (float*)d_ws;
    float* rn2     = ws;                          // 16384 f
    float* csn     = ws + 16384;                  //   512 f
    float* rowsum  = ws + 16896;                  // 16384 f
    float* tgt     = ws + 33280;                  // 16384 f
    float* lossAcc = ws + 49664;                  //     1 f (+3 pad)
    unsigned short* cib_t = (unsigned short*)(ws + 49668);   // 1 MB (16B-aligned)
    unsigned short* ebf_t = cib_t + (size_t)S_ * D_;         // 32 MB

    const size_t need = (size_t)49668 * 4 + (size_t)S_ * D_ * 2 + (size_t)M_ * D_ * 2;

    hipMemsetAsync(lossAcc, 0, sizeof(float), stream);

    if (ws_size >= need) {
        hipMemsetAsync(rowsum, 0, M_ * sizeof(float), stream);
        ge2e_prep_t<<<S_, 256, 0, stream>>>(emb, ebf_t, cib_t, rn2, csn);
        ge2e_gemm_t<<<(M_ / 128) * 4, 256, 0, stream>>>(ebf_t, cib_t, rn2, csn, wp, bp, rowsum, tgt);
        ge2e_lse<<<M_ / 256, 256, 0, stream>>>(rowsum, tgt, wp, bp, lossAcc);
    } else {
        unsigned short* cib = (unsigned short*)(ws + 16900);
        ge2e_prep_fb<<<S_, 256, 0, stream>>>(emb, cib, rn2, csn);
        ge2e_fused_fb<<<M_ / 32, 512, 0, stream>>>(emb, cib, rn2, csn, wp, bp, lossAcc);
    }
    ge2e_final<<<1, 1, 0, stream>>>(lossAcc, (float*)d_out);
}